// Round 1
// 472.275 us; speedup vs baseline: 1.1847x; 1.1847x over previous
//
#include <hip/hip_runtime.h>
#include <hip/hip_bf16.h>

#define NN 100000      // nodes
#define NE 1000000     // edges
#define D  128         // hidden / input dim
#define NC 16          // classes

typedef short short8 __attribute__((ext_vector_type(8)));
typedef float f32x4  __attribute__((ext_vector_type(4)));

__device__ __forceinline__ float bf2f(ushort u) {
  union { unsigned int i; float f; } v; v.i = ((unsigned int)u) << 16; return v.f;
}
__device__ __forceinline__ ushort f2bf(float f) {
  union { float f; unsigned int i; } v; v.f = f;
  unsigned int x = v.i;
  return (ushort)((x + 0x7FFFu + ((x >> 16) & 1u)) >> 16);  // RNE
}

// ---- sniff dtypes: flags[0]=1 if float tensors are f32; flags[1]=1 if idx int64
__global__ void sniff_k(const ushort* __restrict__ xr, const unsigned int* __restrict__ ei,
                        int* __restrict__ flags) {
  if (threadIdx.x != 0 || blockIdx.x != 0) return;
  int f32 = 0;
  for (int i = 0; i < 128; ++i) {
    unsigned int e = ((unsigned int)xr[i] >> 7) & 0xFFu;
    if (e < 97u || e > 157u) f32 = 1;
  }
  flags[0] = f32;
  unsigned int s = 0;
  for (int i = 1; i < 256; i += 2) s |= ei[i];   // int64 < 2^31 => hi words all 0
  flags[1] = (s == 0) ? 1 : 0;
}

// ---- materialize clean int32 indices, clamped to [0,NN) ---------------------
__global__ void convert_idx_k(const int* __restrict__ ei, const int* __restrict__ flags,
                              int* __restrict__ idx, int n) {
  int i = blockIdx.x * blockDim.x + threadIdx.x;
  if (i >= n) return;
  int v = flags[1] ? ei[2 * i] : ei[i];   // int64: take low word
  v = v < 0 ? 0 : (v >= NN ? NN - 1 : v);
  idx[i] = v;
}

// ---- convert x to canonical bf16 -------------------------------------------
__global__ void convert_x_k(const void* __restrict__ xin, const int* __restrict__ flags,
                            ushort* __restrict__ xb) {
  int i = blockIdx.x * blockDim.x + threadIdx.x;
  const int n4 = NN * D / 4;
  if (i >= n4) return;
  ushort4 o;
  if (flags[0]) {
    float4 v = ((const float4*)xin)[i];
    o.x = f2bf(v.x); o.y = f2bf(v.y); o.z = f2bf(v.z); o.w = f2bf(v.w);
  } else {
    o = ((const ushort4*)xin)[i];
  }
  ((ushort4*)xb)[i] = o;
}

// ---- convert all weights/biases to canonical bf16 block --------------------
struct WPtrs { const void* p[10]; };
#define WTOT 102800
__global__ void convert_w_k(WPtrs w, const int* __restrict__ flags, ushort* __restrict__ wb) {
  const int off[10] = {0, 16384, 32768, 49152, 65536, 98304, 102400, 102528, 102656, 102784};
  int i = blockIdx.x * blockDim.x + threadIdx.x;
  if (i >= WTOT) return;
  int seg = 0;
  #pragma unroll
  for (int s2 = 1; s2 < 10; ++s2) if (i >= off[s2]) seg = s2;
  int j = i - off[seg];
  wb[i] = flags[0] ? f2bf(((const float*)w.p[seg])[j]) : ((const ushort*)w.p[seg])[j];
}

// ============================================================================
// CSR build, two-level multisplit (replaces count/scan/bucket random scatter):
//   coarse bucket = dst >> BSH (512 nodes, 196 buckets, ~5100 edges each)
//   phase 1: global bucket histogram (LDS-aggregated) + scan -> bucket bases
//   phase 2: msplit_k — per-block LDS binning, one chunk atomic per
//            (block,bucket); (src,dst) pairs written in ~160B contiguous runs
//   phase 3: csr_k — one block per bucket; per-node count + scan + scatter all
//            in LDS, coalesced nbr/off writes. Zero global fine-grain atomics.
// ============================================================================
#define BSH 9
#define NBKT ((NN + 511) >> BSH)                 // 196
#define MS_NBLK 256
#define MS_EPB ((NE + MS_NBLK - 1) / MS_NBLK)    // 3907
#define CSR_CAP 8192

__global__ __launch_bounds__(256) void hist_k(const int* __restrict__ dst,
                                              int* __restrict__ bhist) {
  __shared__ int h[NBKT];
  for (int t = threadIdx.x; t < NBKT; t += 256) h[t] = 0;
  __syncthreads();
  const int stride = gridDim.x * blockDim.x;
  for (int i = blockIdx.x * blockDim.x + threadIdx.x; i < NE; i += stride)
    atomicAdd(&h[dst[i] >> BSH], 1);
  __syncthreads();
  for (int t = threadIdx.x; t < NBKT; t += 256) if (h[t]) atomicAdd(&bhist[t], h[t]);
}

__global__ __launch_bounds__(256) void scanb_k(const int* __restrict__ bhist,
                                               int* __restrict__ bstart,
                                               int* __restrict__ bcur) {
  __shared__ int tmp[256];
  const int t = threadIdx.x;
  int v = (t < NBKT) ? bhist[t] : 0;
  tmp[t] = v;
  __syncthreads();
  for (int s = 1; s < 256; s <<= 1) {
    int u = (t >= s) ? tmp[t - s] : 0;
    __syncthreads();
    tmp[t] += u;
    __syncthreads();
  }
  if (t < NBKT) {
    int ex = tmp[t] - v;
    bstart[t] = ex;
    bcur[t] = ex;
  }
  if (t == NBKT - 1) bstart[NBKT] = tmp[t];
}

__global__ __launch_bounds__(512) void msplit_k(const int* __restrict__ src,
                                                const int* __restrict__ dst,
                                                int* __restrict__ bcur,
                                                int2* __restrict__ ebuf) {
  __shared__ int2 ep[MS_EPB];        // ~31.3 KiB
  __shared__ int hist[NBKT];
  __shared__ int gbase[NBKT];
  const int e0 = blockIdx.x * MS_EPB;
  int n = NE - e0; if (n > MS_EPB) n = MS_EPB;
  for (int t = threadIdx.x; t < NBKT; t += 512) hist[t] = 0;
  __syncthreads();
  for (int t = threadIdx.x; t < n; t += 512) {
    int s = src[e0 + t], d = dst[e0 + t];
    ep[t] = make_int2(s, d);
    atomicAdd(&hist[d >> BSH], 1);
  }
  __syncthreads();
  for (int t = threadIdx.x; t < NBKT; t += 512) {
    gbase[t] = atomicAdd(&bcur[t], hist[t]);   // one chunk per (block,bucket)
    hist[t] = 0;                               // reuse as local cursor
  }
  __syncthreads();
  for (int t = threadIdx.x; t < n; t += 512) {
    int2 p = ep[t];
    int b = p.y >> BSH;
    int loc = atomicAdd(&hist[b], 1);
    ebuf[gbase[b] + loc] = p;                  // contiguous within chunk
  }
}

__global__ __launch_bounds__(512) void csr_k(const int2* __restrict__ ebuf,
                                             const int* __restrict__ bstart,
                                             int* __restrict__ off,
                                             int* __restrict__ nbr) {
  __shared__ int cnt_s[512];
  __shared__ int ofs_s[512];
  __shared__ int lnbr[CSR_CAP];      // 32 KiB staging
  const int b = blockIdx.x;
  const int n0 = b << BSH;
  int nn = NN - n0; if (nn > 512) nn = 512;
  const int e0 = bstart[b], e1 = bstart[b + 1];
  const int n = e1 - e0;
  const int t = threadIdx.x;
  cnt_s[t] = 0;
  __syncthreads();
  for (int i = t; i < n; i += 512)
    atomicAdd(&cnt_s[ebuf[e0 + i].y - n0], 1);
  __syncthreads();
  int v = cnt_s[t];
  ofs_s[t] = v;
  __syncthreads();
  for (int s = 1; s < 512; s <<= 1) {          // inclusive Hillis-Steele
    int u = (t >= s) ? ofs_s[t - s] : 0;
    __syncthreads();
    ofs_s[t] += u;
    __syncthreads();
  }
  const int excl = ofs_s[t] - v;
  if (t < nn) off[n0 + t] = e0 + excl;
  if (b == gridDim.x - 1 && t == 0) off[NN] = e1;   // == NE
  cnt_s[t] = excl;                 // becomes scatter cursor
  __syncthreads();
  if (n <= CSR_CAP) {
    for (int i = t; i < n; i += 512) {
      int2 p = ebuf[e0 + i];
      int loc = atomicAdd(&cnt_s[p.y - n0], 1);
      lnbr[loc] = p.x;
    }
    __syncthreads();
    for (int i = t; i < n; i += 512) nbr[e0 + i] = lnbr[i];   // coalesced
  } else {                         // safety fallback (never expected)
    for (int i = t; i < n; i += 512) {
      int2 p = ebuf[e0 + i];
      int loc = atomicAdd(&cnt_s[p.y - n0], 1);
      nbr[e0 + loc] = p.x;
    }
  }
}

// ---- segmented mean: one wave per node, 64 lanes x 2 f32 acc = 128 dims -----
__global__ __launch_bounds__(256) void agg_k(
    const ushort* __restrict__ X, const int* __restrict__ nbr,
    const int* __restrict__ off, ushort* __restrict__ mean) {
  const int wave = threadIdx.x >> 6, lane = threadIdx.x & 63;
  const int node = blockIdx.x * 4 + wave;
  if (node >= NN) return;
  const int j0 = off[node], j1 = off[node + 1];
  float a0 = 0.f, a1 = 0.f;
  int j = j0;
  for (; j + 1 < j1; j += 2) {    // 2 edges/iter for load ILP
    int s0 = nbr[j], s1 = nbr[j + 1];
    unsigned int v0 = *(const unsigned int*)(X + (size_t)s0 * D + lane * 2);
    unsigned int v1 = *(const unsigned int*)(X + (size_t)s1 * D + lane * 2);
    a0 += bf2f((ushort)(v0 & 0xffffu)) + bf2f((ushort)(v1 & 0xffffu));
    a1 += bf2f((ushort)(v0 >> 16))     + bf2f((ushort)(v1 >> 16));
  }
  if (j < j1) {
    unsigned int v0 = *(const unsigned int*)(X + (size_t)nbr[j] * D + lane * 2);
    a0 += bf2f((ushort)(v0 & 0xffffu));
    a1 += bf2f((ushort)(v0 >> 16));
  }
  int deg = j1 - j0;
  float inv = 1.f / (float)(deg > 1 ? deg : 1);
  unsigned int o = (unsigned int)f2bf(a0 * inv) | ((unsigned int)f2bf(a1 * inv) << 16);
  *(unsigned int*)(mean + (size_t)node * D + lane * 2) = o;
}

// ---- Y = relu(A1@W1^T + A2@W2^T + bias), all [.,128] -----------------------
__global__ __launch_bounds__(256) void gemm_dual(
    const ushort* __restrict__ A1, const ushort* __restrict__ A2,
    const ushort* __restrict__ W1, const ushort* __restrict__ W2, int ldw,
    const ushort* __restrict__ bias, ushort* __restrict__ Y, int nrows)
{
  __shared__ ushort wlds[32 * 64 * 8];   // 32 KiB
  const int tid = threadIdx.x;
  const int wave = tid >> 6, lane = tid & 63;
  const int l15 = lane & 15, q = lane >> 4;
  const int m0 = blockIdx.x * 128 + wave * 32;

  f32x4 acc[2][8];
  #pragma unroll
  for (int rt = 0; rt < 2; ++rt)
    #pragma unroll
    for (int c = 0; c < 8; ++c) acc[rt][c] = (f32x4){0.f, 0.f, 0.f, 0.f};

  for (int phase = 0; phase < 2; ++phase) {
    const ushort* W = phase ? W2 : W1;
    const ushort* A = phase ? A2 : A1;
    __syncthreads();
    #pragma unroll
    for (int it = 0; it < 8; ++it) {
      int combo = it * 4 + wave;         // c = combo>>2, ks = combo&3
      int c = combo >> 2, ks = combo & 3;
      *(uint4*)(&wlds[(combo * 64 + lane) * 8]) =
          *(const uint4*)(W + (size_t)(c * 16 + l15) * ldw + ks * 32 + q * 8);
    }
    __syncthreads();
    #pragma unroll
    for (int ks = 0; ks < 4; ++ks) {
      short8 af[2];
      #pragma unroll
      for (int rt = 0; rt < 2; ++rt) {
        int row = m0 + rt * 16 + l15;
        if (row > nrows - 1) row = nrows - 1;   // clamp (stores are guarded)
        af[rt] = *(const short8*)(A + (size_t)row * D + ks * 32 + q * 8);
      }
      #pragma unroll
      for (int c = 0; c < 8; ++c) {
        short8 bf = *(const short8*)(&wlds[((c * 4 + ks) * 64 + lane) * 8]);
        acc[0][c] = __builtin_amdgcn_mfma_f32_16x16x32_bf16(af[0], bf, acc[0][c], 0, 0, 0);
        acc[1][c] = __builtin_amdgcn_mfma_f32_16x16x32_bf16(af[1], bf, acc[1][c], 0, 0, 0);
      }
    }
  }
  // C/D layout: col = lane&15, row = (lane>>4)*4 + r   [m89-verified]
  #pragma unroll
  for (int c = 0; c < 8; ++c) {
    float b = bf2f(bias[c * 16 + l15]);
    #pragma unroll
    for (int rt = 0; rt < 2; ++rt) {
      #pragma unroll
      for (int r = 0; r < 4; ++r) {
        int row = m0 + rt * 16 + q * 4 + r;
        if (row < nrows) {
          float v = acc[rt][c][r] + b;
          v = v > 0.f ? v : 0.f;
          Y[(size_t)row * D + c * 16 + l15] = f2bf(v);
        }
      }
    }
  }
}

// ---- P[node, 0:16] = x2[node] @ Wo[:, 0:128]^T ; P[node,16:32] = @ Wo[:,128:]^T
// one wave = 16 rows x 32 cols, K=128; f32 output (exact edge sums later)
__global__ __launch_bounds__(256) void gemm_po(
    const ushort* __restrict__ X2, const ushort* __restrict__ Wo, float* __restrict__ P)
{
  __shared__ ushort wlds[8 * 64 * 8];    // 8 KiB: combo = c*4+ks
  const int tid = threadIdx.x, wave = tid >> 6, lane = tid & 63;
  const int l15 = lane & 15, q = lane >> 4;
  const int m0 = blockIdx.x * 64 + wave * 16;
  #pragma unroll
  for (int it = 0; it < 2; ++it) {
    int combo = it * 4 + wave;           // c = combo>>2 (col half), ks = combo&3
    int c = combo >> 2, ks = combo & 3;
    *(uint4*)(&wlds[(combo * 64 + lane) * 8]) =
        *(const uint4*)(Wo + (size_t)l15 * 256 + c * 128 + ks * 32 + q * 8);
  }
  __syncthreads();
  f32x4 acc[2] = {(f32x4){0.f,0.f,0.f,0.f}, (f32x4){0.f,0.f,0.f,0.f}};
  #pragma unroll
  for (int ks = 0; ks < 4; ++ks) {
    int row = m0 + l15; if (row > NN - 1) row = NN - 1;
    short8 af = *(const short8*)(X2 + (size_t)row * D + ks * 32 + q * 8);
    #pragma unroll
    for (int c = 0; c < 2; ++c) {
      short8 bf = *(const short8*)(&wlds[((c * 4 + ks) * 64 + lane) * 8]);
      acc[c] = __builtin_amdgcn_mfma_f32_16x16x32_bf16(af, bf, acc[c], 0, 0, 0);
    }
  }
  #pragma unroll
  for (int c = 0; c < 2; ++c)
    #pragma unroll
    for (int r = 0; r < 4; ++r) {
      int row = m0 + q * 4 + r;
      if (row < NN) P[(size_t)row * 32 + c * 16 + l15] = acc[c][r];
    }
}

// ---- out[e,c] = P[src[e]][c] + P[dst[e]][16+c] + bo[c] ---------------------
__global__ __launch_bounds__(256) void edge_sum_k(
    const float* __restrict__ P, const int* __restrict__ src, const int* __restrict__ dst,
    const ushort* __restrict__ bo, const int* __restrict__ flags,
    void* __restrict__ outv, int E)
{
  int gid = blockIdx.x * blockDim.x + threadIdx.x;
  if (gid >= E * 4) return;
  int e = gid >> 2, cq = (gid & 3) * 4;
  int s = src[e], d = dst[e];
  float4 a = *(const float4*)(P + (size_t)s * 32 + cq);
  float4 b = *(const float4*)(P + (size_t)d * 32 + 16 + cq);
  float4 o;
  o.x = a.x + b.x + bf2f(bo[cq + 0]);
  o.y = a.y + b.y + bf2f(bo[cq + 1]);
  o.z = a.z + b.z + bf2f(bo[cq + 2]);
  o.w = a.w + b.w + bf2f(bo[cq + 3]);
  if (flags[0]) {
    ((float4*)outv)[gid] = o;
  } else {
    ushort4 u;
    u.x = f2bf(o.x); u.y = f2bf(o.y); u.z = f2bf(o.z); u.w = f2bf(o.w);
    ((ushort4*)outv)[gid] = u;
  }
}

extern "C" void kernel_launch(void* const* d_in, const int* in_sizes, int n_in,
                              void* d_out, int out_size, void* d_ws, size_t ws_size,
                              hipStream_t stream) {
  const void* x_in = d_in[0];
  const int*  ei   = (const int*)d_in[1];

  // workspace layout (bytes): total ~64.6 MB
  char* ws = (char*)d_ws;
  int*    idx   = (int*)(ws + 0);              //  8,000,000 (src | dst)
  int*    bhist = (int*)(ws + 8000000);        //        784 (NBKT)
  int*    flags = (int*)(ws + 8400000);        //        256
  ushort* wb    = (ushort*)(ws + 8400256);     //    205,600
  int*    off   = (int*)(ws + 8605856);        //    400,004
  int*    bstart= (int*)(ws + 9005872);        //        788 (NBKT+1)
  int*    nbr   = (int*)(ws + 9405872);        //  4,000,000
  int*    bcur  = (int*)(ws + 13405872);       //        784
  ushort* buf1  = (ushort*)(ws + 13407440);    // 25,600,000 (ebuf -> h -> P)
  ushort* buf2  = (ushort*)(ws + 39007440);    // 25,600,000 (xb / meanL1 / x2)
  ushort* dscr  = (ushort*)d_out;              // d_out scratch: meanL0 / x1
  float*  P     = (float*)buf1;                // alias: buf1 dead after last gemm_dual
  int2*   ebuf  = (int2*)buf1;                 // alias: dead before first gemm_dual

  int* src = idx;
  int* dst = idx + NE;

  ushort* Wl0 = wb + 0,      *Wr0 = wb + 16384, *Wl1 = wb + 32768, *Wr1 = wb + 49152;
  ushort* Wc  = wb + 65536,  *Wo  = wb + 98304;
  ushort* bl0 = wb + 102400, *bl1 = wb + 102528, *bc = wb + 102656, *bo = wb + 102784;

  WPtrs w;
  w.p[0] = d_in[2];  w.p[1] = d_in[4];  w.p[2] = d_in[5];  w.p[3] = d_in[7];
  w.p[4] = d_in[8];  w.p[5] = d_in[10]; w.p[6] = d_in[3];  w.p[7] = d_in[6];
  w.p[8] = d_in[9];  w.p[9] = d_in[11];

  const int gblocks = (NN + 127) / 128;        // 782
  const int n4 = NN * D / 4;
  const int agrid = (NN + 3) / 4;              // 25,000 (4 nodes/block)

  sniff_k<<<1, 64, 0, stream>>>((const ushort*)x_in, (const unsigned int*)ei, flags);
  convert_idx_k<<<(2 * NE + 255) / 256, 256, 0, stream>>>(ei, flags, idx, 2 * NE);
  convert_x_k<<<(n4 + 255) / 256, 256, 0, stream>>>(x_in, flags, buf2);
  convert_w_k<<<(WTOT + 255) / 256, 256, 0, stream>>>(w, flags, wb);

  // ---- build CSR via two-level multisplit (LDS atomics, coalesced writes) --
  (void)hipMemsetAsync(bhist, 0, NBKT * sizeof(int), stream);
  hist_k<<<256, 256, 0, stream>>>(dst, bhist);
  scanb_k<<<1, 256, 0, stream>>>(bhist, bstart, bcur);
  msplit_k<<<MS_NBLK, 512, 0, stream>>>(src, dst, bcur, ebuf);
  csr_k<<<NBKT, 512, 0, stream>>>(ebuf, bstart, off, nbr);

  // ---- layer 0: x=buf2 -> mean=dscr -> h=buf1 -> x1=dscr -------------------
  agg_k<<<agrid, 256, 0, stream>>>(buf2, nbr, off, dscr);
  gemm_dual<<<gblocks, 256, 0, stream>>>(dscr, buf2, Wl0, Wr0, D, bl0, buf1, NN);      // h
  gemm_dual<<<gblocks, 256, 0, stream>>>(buf2, buf1, Wc, Wc + D, 2 * D, bc, dscr, NN); // x1

  // ---- layer 1: x1=dscr -> mean=buf2 -> h=buf1 -> x2=buf2 ------------------
  agg_k<<<agrid, 256, 0, stream>>>(dscr, nbr, off, buf2);
  gemm_dual<<<gblocks, 256, 0, stream>>>(buf2, dscr, Wl1, Wr1, D, bl1, buf1, NN);      // h
  gemm_dual<<<gblocks, 256, 0, stream>>>(dscr, buf1, Wc, Wc + D, 2 * D, bc, buf2, NN); // x2

  // ---- edge classifier: factored P-GEMM + gather-sum -----------------------
  gemm_po<<<(NN + 63) / 64, 256, 0, stream>>>(buf2, Wo, P);
  edge_sum_k<<<(4 * NE + 255) / 256, 256, 0, stream>>>(P, src, dst, bo, flags, d_out, NE);
}

// Round 2
// 433.503 us; speedup vs baseline: 1.2907x; 1.0894x over previous
//
#include <hip/hip_runtime.h>
#include <hip/hip_bf16.h>

#define NN 100000      // nodes
#define NE 1000000     // edges
#define D  128         // hidden / input dim
#define NC 16          // classes

typedef short short8 __attribute__((ext_vector_type(8)));
typedef float f32x4  __attribute__((ext_vector_type(4)));

__device__ __forceinline__ float bf2f(ushort u) {
  union { unsigned int i; float f; } v; v.i = ((unsigned int)u) << 16; return v.f;
}
__device__ __forceinline__ ushort f2bf(float f) {
  union { float f; unsigned int i; } v; v.f = f;
  unsigned int x = v.i;
  return (ushort)((x + 0x7FFFu + ((x >> 16) & 1u)) >> 16);  // RNE
}

// ---- sniff dtypes: flags[0]=1 if float tensors are f32; flags[1]=1 if idx int64
__global__ void sniff_k(const ushort* __restrict__ xr, const unsigned int* __restrict__ ei,
                        int* __restrict__ flags) {
  if (threadIdx.x != 0 || blockIdx.x != 0) return;
  int f32 = 0;
  for (int i = 0; i < 128; ++i) {
    unsigned int e = ((unsigned int)xr[i] >> 7) & 0xFFu;
    if (e < 97u || e > 157u) f32 = 1;
  }
  flags[0] = f32;
  unsigned int s = 0;
  for (int i = 1; i < 256; i += 2) s |= ei[i];   // int64 < 2^31 => hi words all 0
  flags[1] = (s == 0) ? 1 : 0;
}

// ---- materialize clean int32 indices, clamped to [0,NN) ---------------------
__global__ void convert_idx_k(const int* __restrict__ ei, const int* __restrict__ flags,
                              int* __restrict__ idx, int n) {
  int i = blockIdx.x * blockDim.x + threadIdx.x;
  if (i >= n) return;
  int v = flags[1] ? ei[2 * i] : ei[i];   // int64: take low word
  v = v < 0 ? 0 : (v >= NN ? NN - 1 : v);
  idx[i] = v;
}

// ---- convert x to canonical bf16 -------------------------------------------
__global__ void convert_x_k(const void* __restrict__ xin, const int* __restrict__ flags,
                            ushort* __restrict__ xb) {
  int i = blockIdx.x * blockDim.x + threadIdx.x;
  const int n4 = NN * D / 4;
  if (i >= n4) return;
  ushort4 o;
  if (flags[0]) {
    float4 v = ((const float4*)xin)[i];
    o.x = f2bf(v.x); o.y = f2bf(v.y); o.z = f2bf(v.z); o.w = f2bf(v.w);
  } else {
    o = ((const ushort4*)xin)[i];
  }
  ((ushort4*)xb)[i] = o;
}

// ---- convert all weights/biases to canonical bf16 block --------------------
struct WPtrs { const void* p[10]; };
#define WTOT 102800
__global__ void convert_w_k(WPtrs w, const int* __restrict__ flags, ushort* __restrict__ wb) {
  const int off[10] = {0, 16384, 32768, 49152, 65536, 98304, 102400, 102528, 102656, 102784};
  int i = blockIdx.x * blockDim.x + threadIdx.x;
  if (i >= WTOT) return;
  int seg = 0;
  #pragma unroll
  for (int s2 = 1; s2 < 10; ++s2) if (i >= off[s2]) seg = s2;
  int j = i - off[seg];
  wb[i] = flags[0] ? f2bf(((const float*)w.p[seg])[j]) : ((const ushort*)w.p[seg])[j];
}

// ============================================================================
// CSR build, two-level multisplit
// ============================================================================
#define BSH 9
#define NBKT ((NN + 511) >> BSH)                 // 196
#define MS_NBLK 256
#define MS_EPB ((NE + MS_NBLK - 1) / MS_NBLK)    // 3907
#define CSR_CAP 8192

__global__ __launch_bounds__(256) void hist_k(const int* __restrict__ dst,
                                              int* __restrict__ bhist) {
  __shared__ int h[NBKT];
  for (int t = threadIdx.x; t < NBKT; t += 256) h[t] = 0;
  __syncthreads();
  const int stride = gridDim.x * blockDim.x;
  for (int i = blockIdx.x * blockDim.x + threadIdx.x; i < NE; i += stride)
    atomicAdd(&h[dst[i] >> BSH], 1);
  __syncthreads();
  for (int t = threadIdx.x; t < NBKT; t += 256) if (h[t]) atomicAdd(&bhist[t], h[t]);
}

__global__ __launch_bounds__(256) void scanb_k(const int* __restrict__ bhist,
                                               int* __restrict__ bstart,
                                               int* __restrict__ bcur) {
  __shared__ int tmp[256];
  const int t = threadIdx.x;
  int v = (t < NBKT) ? bhist[t] : 0;
  tmp[t] = v;
  __syncthreads();
  for (int s = 1; s < 256; s <<= 1) {
    int u = (t >= s) ? tmp[t - s] : 0;
    __syncthreads();
    tmp[t] += u;
    __syncthreads();
  }
  if (t < NBKT) {
    int ex = tmp[t] - v;
    bstart[t] = ex;
    bcur[t] = ex;
  }
  if (t == NBKT - 1) bstart[NBKT] = tmp[t];
}

__global__ __launch_bounds__(512) void msplit_k(const int* __restrict__ src,
                                                const int* __restrict__ dst,
                                                int* __restrict__ bcur,
                                                int2* __restrict__ ebuf) {
  __shared__ int2 ep[MS_EPB];        // ~31.3 KiB
  __shared__ int hist[NBKT];
  __shared__ int gbase[NBKT];
  const int e0 = blockIdx.x * MS_EPB;
  int n = NE - e0; if (n > MS_EPB) n = MS_EPB;
  for (int t = threadIdx.x; t < NBKT; t += 512) hist[t] = 0;
  __syncthreads();
  for (int t = threadIdx.x; t < n; t += 512) {
    int s = src[e0 + t], d = dst[e0 + t];
    ep[t] = make_int2(s, d);
    atomicAdd(&hist[d >> BSH], 1);
  }
  __syncthreads();
  for (int t = threadIdx.x; t < NBKT; t += 512) {
    gbase[t] = atomicAdd(&bcur[t], hist[t]);   // one chunk per (block,bucket)
    hist[t] = 0;                               // reuse as local cursor
  }
  __syncthreads();
  for (int t = threadIdx.x; t < n; t += 512) {
    int2 p = ep[t];
    int b = p.y >> BSH;
    int loc = atomicAdd(&hist[b], 1);
    ebuf[gbase[b] + loc] = p;                  // contiguous within chunk
  }
}

__global__ __launch_bounds__(512) void csr_k(const int2* __restrict__ ebuf,
                                             const int* __restrict__ bstart,
                                             int* __restrict__ off,
                                             int* __restrict__ nbr) {
  __shared__ int cnt_s[512];
  __shared__ int ofs_s[512];
  __shared__ int lnbr[CSR_CAP];      // 32 KiB staging
  const int b = blockIdx.x;
  const int n0 = b << BSH;
  int nn = NN - n0; if (nn > 512) nn = 512;
  const int e0 = bstart[b], e1 = bstart[b + 1];
  const int n = e1 - e0;
  const int t = threadIdx.x;
  cnt_s[t] = 0;
  __syncthreads();
  for (int i = t; i < n; i += 512)
    atomicAdd(&cnt_s[ebuf[e0 + i].y - n0], 1);
  __syncthreads();
  int v = cnt_s[t];
  ofs_s[t] = v;
  __syncthreads();
  for (int s = 1; s < 512; s <<= 1) {          // inclusive Hillis-Steele
    int u = (t >= s) ? ofs_s[t - s] : 0;
    __syncthreads();
    ofs_s[t] += u;
    __syncthreads();
  }
  const int excl = ofs_s[t] - v;
  if (t < nn) off[n0 + t] = e0 + excl;
  if (b == gridDim.x - 1 && t == 0) off[NN] = e1;   // == NE
  cnt_s[t] = excl;                 // becomes scatter cursor
  __syncthreads();
  if (n <= CSR_CAP) {
    for (int i = t; i < n; i += 512) {
      int2 p = ebuf[e0 + i];
      int loc = atomicAdd(&cnt_s[p.y - n0], 1);
      lnbr[loc] = p.x;
    }
    __syncthreads();
    for (int i = t; i < n; i += 512) nbr[e0 + i] = lnbr[i];   // coalesced
  } else {                         // safety fallback (never expected)
    for (int i = t; i < n; i += 512) {
      int2 p = ebuf[e0 + i];
      int loc = atomicAdd(&cnt_s[p.y - n0], 1);
      nbr[e0 + loc] = p.x;
    }
  }
}

// ---- segmented mean: one wave per node; 4 edge-groups x 16 lanes x 16B -----
// lane = g*16 + l15: group g handles edges j0+g, j0+g+4, ...; lane covers
// dims [l15*8, l15*8+8) via one uint4 (8 bf16). 8 edges in flight (unroll 2).
// Cross-group reduce: shfl_xor 16/32; lanes 0..15 write the row (uint4).
__global__ __launch_bounds__(256) void agg_k(
    const ushort* __restrict__ X, const int* __restrict__ nbr,
    const int* __restrict__ off, ushort* __restrict__ mean) {
  const int wave = threadIdx.x >> 6, lane = threadIdx.x & 63;
  const int node = blockIdx.x * 4 + wave;
  if (node >= NN) return;
  const int j0 = off[node], j1 = off[node + 1];
  const int g = lane >> 4, l15 = lane & 15;
  float a[8];
  #pragma unroll
  for (int k = 0; k < 8; ++k) a[k] = 0.f;
  int j = j0 + g;
  for (; j + 4 < j1; j += 8) {     // 2 edges per group in flight
    int s0 = nbr[j], s1 = nbr[j + 4];
    uint4 v0 = *(const uint4*)(X + (size_t)s0 * D + l15 * 8);
    uint4 v1 = *(const uint4*)(X + (size_t)s1 * D + l15 * 8);
    unsigned int w0[4] = {v0.x, v0.y, v0.z, v0.w};
    unsigned int w1[4] = {v1.x, v1.y, v1.z, v1.w};
    #pragma unroll
    for (int k = 0; k < 4; ++k) {
      union { unsigned int u; float f; } lo0, hi0, lo1, hi1;
      lo0.u = w0[k] << 16; hi0.u = w0[k] & 0xffff0000u;
      lo1.u = w1[k] << 16; hi1.u = w1[k] & 0xffff0000u;
      a[2 * k]     += lo0.f + lo1.f;
      a[2 * k + 1] += hi0.f + hi1.f;
    }
  }
  if (j < j1) {
    uint4 v0 = *(const uint4*)(X + (size_t)nbr[j] * D + l15 * 8);
    unsigned int w0[4] = {v0.x, v0.y, v0.z, v0.w};
    #pragma unroll
    for (int k = 0; k < 4; ++k) {
      union { unsigned int u; float f; } lo0, hi0;
      lo0.u = w0[k] << 16; hi0.u = w0[k] & 0xffff0000u;
      a[2 * k]     += lo0.f;
      a[2 * k + 1] += hi0.f;
    }
  }
  #pragma unroll
  for (int k = 0; k < 8; ++k) {    // reduce the 4 edge-groups
    a[k] += __shfl_xor(a[k], 16, 64);
    a[k] += __shfl_xor(a[k], 32, 64);
  }
  if (g == 0) {
    int deg = j1 - j0;
    float inv = 1.f / (float)(deg > 1 ? deg : 1);
    uint4 o;
    o.x = (unsigned int)f2bf(a[0] * inv) | ((unsigned int)f2bf(a[1] * inv) << 16);
    o.y = (unsigned int)f2bf(a[2] * inv) | ((unsigned int)f2bf(a[3] * inv) << 16);
    o.z = (unsigned int)f2bf(a[4] * inv) | ((unsigned int)f2bf(a[5] * inv) << 16);
    o.w = (unsigned int)f2bf(a[6] * inv) | ((unsigned int)f2bf(a[7] * inv) << 16);
    *(uint4*)(mean + (size_t)node * D + l15 * 8) = o;
  }
}

// ---- Y = relu(A1@W1^T + A2@W2^T + bias), all [.,128] -----------------------
__global__ __launch_bounds__(256) void gemm_dual(
    const ushort* __restrict__ A1, const ushort* __restrict__ A2,
    const ushort* __restrict__ W1, const ushort* __restrict__ W2, int ldw,
    const ushort* __restrict__ bias, ushort* __restrict__ Y, int nrows)
{
  __shared__ ushort wlds[32 * 64 * 8];   // 32 KiB
  const int tid = threadIdx.x;
  const int wave = tid >> 6, lane = tid & 63;
  const int l15 = lane & 15, q = lane >> 4;
  const int m0 = blockIdx.x * 128 + wave * 32;

  f32x4 acc[2][8];
  #pragma unroll
  for (int rt = 0; rt < 2; ++rt)
    #pragma unroll
    for (int c = 0; c < 8; ++c) acc[rt][c] = (f32x4){0.f, 0.f, 0.f, 0.f};

  for (int phase = 0; phase < 2; ++phase) {
    const ushort* W = phase ? W2 : W1;
    const ushort* A = phase ? A2 : A1;
    __syncthreads();
    #pragma unroll
    for (int it = 0; it < 8; ++it) {
      int combo = it * 4 + wave;         // c = combo>>2, ks = combo&3
      int c = combo >> 2, ks = combo & 3;
      *(uint4*)(&wlds[(combo * 64 + lane) * 8]) =
          *(const uint4*)(W + (size_t)(c * 16 + l15) * ldw + ks * 32 + q * 8);
    }
    __syncthreads();
    #pragma unroll
    for (int ks = 0; ks < 4; ++ks) {
      short8 af[2];
      #pragma unroll
      for (int rt = 0; rt < 2; ++rt) {
        int row = m0 + rt * 16 + l15;
        if (row > nrows - 1) row = nrows - 1;   // clamp (stores are guarded)
        af[rt] = *(const short8*)(A + (size_t)row * D + ks * 32 + q * 8);
      }
      #pragma unroll
      for (int c = 0; c < 8; ++c) {
        short8 bf = *(const short8*)(&wlds[((c * 4 + ks) * 64 + lane) * 8]);
        acc[0][c] = __builtin_amdgcn_mfma_f32_16x16x32_bf16(af[0], bf, acc[0][c], 0, 0, 0);
        acc[1][c] = __builtin_amdgcn_mfma_f32_16x16x32_bf16(af[1], bf, acc[1][c], 0, 0, 0);
      }
    }
  }
  // C/D layout: col = lane&15, row = (lane>>4)*4 + r   [m89-verified]
  #pragma unroll
  for (int c = 0; c < 8; ++c) {
    float b = bf2f(bias[c * 16 + l15]);
    #pragma unroll
    for (int rt = 0; rt < 2; ++rt) {
      #pragma unroll
      for (int r = 0; r < 4; ++r) {
        int row = m0 + rt * 16 + q * 4 + r;
        if (row < nrows) {
          float v = acc[rt][c][r] + b;
          v = v > 0.f ? v : 0.f;
          Y[(size_t)row * D + c * 16 + l15] = f2bf(v);
        }
      }
    }
  }
}

// ---- P[node, 0:16] = x2[node] @ Wo[:, 0:128]^T ; P[node,16:32] = @ Wo[:,128:]^T
__global__ __launch_bounds__(256) void gemm_po(
    const ushort* __restrict__ X2, const ushort* __restrict__ Wo, float* __restrict__ P)
{
  __shared__ ushort wlds[8 * 64 * 8];    // 8 KiB: combo = c*4+ks
  const int tid = threadIdx.x, wave = tid >> 6, lane = tid & 63;
  const int l15 = lane & 15, q = lane >> 4;
  const int m0 = blockIdx.x * 64 + wave * 16;
  #pragma unroll
  for (int it = 0; it < 2; ++it) {
    int combo = it * 4 + wave;           // c = combo>>2 (col half), ks = combo&3
    int c = combo >> 2, ks = combo & 3;
    *(uint4*)(&wlds[(combo * 64 + lane) * 8]) =
        *(const uint4*)(Wo + (size_t)l15 * 256 + c * 128 + ks * 32 + q * 8);
  }
  __syncthreads();
  f32x4 acc[2] = {(f32x4){0.f,0.f,0.f,0.f}, (f32x4){0.f,0.f,0.f,0.f}};
  #pragma unroll
  for (int ks = 0; ks < 4; ++ks) {
    int row = m0 + l15; if (row > NN - 1) row = NN - 1;
    short8 af = *(const short8*)(X2 + (size_t)row * D + ks * 32 + q * 8);
    #pragma unroll
    for (int c = 0; c < 2; ++c) {
      short8 bf = *(const short8*)(&wlds[((c * 4 + ks) * 64 + lane) * 8]);
      acc[c] = __builtin_amdgcn_mfma_f32_16x16x32_bf16(af, bf, acc[c], 0, 0, 0);
    }
  }
  #pragma unroll
  for (int c = 0; c < 2; ++c)
    #pragma unroll
    for (int r = 0; r < 4; ++r) {
      int row = m0 + q * 4 + r;
      if (row < NN) P[(size_t)row * 32 + c * 16 + l15] = acc[c][r];
    }
}

// ---- out[e,c] = P[src[e]][c] + P[dst[e]][16+c] + bo[c] ---------------------
__global__ __launch_bounds__(256) void edge_sum_k(
    const float* __restrict__ P, const int* __restrict__ src, const int* __restrict__ dst,
    const ushort* __restrict__ bo, const int* __restrict__ flags,
    void* __restrict__ outv, int E)
{
  int gid = blockIdx.x * blockDim.x + threadIdx.x;
  if (gid >= E * 4) return;
  int e = gid >> 2, cq = (gid & 3) * 4;
  int s = src[e], d = dst[e];
  float4 a = *(const float4*)(P + (size_t)s * 32 + cq);
  float4 b = *(const float4*)(P + (size_t)d * 32 + 16 + cq);
  float4 o;
  o.x = a.x + b.x + bf2f(bo[cq + 0]);
  o.y = a.y + b.y + bf2f(bo[cq + 1]);
  o.z = a.z + b.z + bf2f(bo[cq + 2]);
  o.w = a.w + b.w + bf2f(bo[cq + 3]);
  if (flags[0]) {
    ((float4*)outv)[gid] = o;
  } else {
    ushort4 u;
    u.x = f2bf(o.x); u.y = f2bf(o.y); u.z = f2bf(o.z); u.w = f2bf(o.w);
    ((ushort4*)outv)[gid] = u;
  }
}

extern "C" void kernel_launch(void* const* d_in, const int* in_sizes, int n_in,
                              void* d_out, int out_size, void* d_ws, size_t ws_size,
                              hipStream_t stream) {
  const void* x_in = d_in[0];
  const int*  ei   = (const int*)d_in[1];

  // workspace layout (bytes): total ~64.6 MB
  char* ws = (char*)d_ws;
  int*    idx   = (int*)(ws + 0);              //  8,000,000 (src | dst)
  int*    bhist = (int*)(ws + 8000000);        //        784 (NBKT)
  int*    flags = (int*)(ws + 8400000);        //        256
  ushort* wb    = (ushort*)(ws + 8400256);     //    205,600
  int*    off   = (int*)(ws + 8605856);        //    400,004
  int*    bstart= (int*)(ws + 9005872);        //        788 (NBKT+1)
  int*    nbr   = (int*)(ws + 9405872);        //  4,000,000
  int*    bcur  = (int*)(ws + 13405872);       //        784
  ushort* buf1  = (ushort*)(ws + 13407440);    // 25,600,000 (ebuf -> h -> P)
  ushort* buf2  = (ushort*)(ws + 39007440);    // 25,600,000 (xb / meanL1 / x2)
  ushort* dscr  = (ushort*)d_out;              // d_out scratch: meanL0 / x1
  float*  P     = (float*)buf1;                // alias: buf1 dead after last gemm_dual
  int2*   ebuf  = (int2*)buf1;                 // alias: dead before first gemm_dual

  int* src = idx;
  int* dst = idx + NE;

  ushort* Wl0 = wb + 0,      *Wr0 = wb + 16384, *Wl1 = wb + 32768, *Wr1 = wb + 49152;
  ushort* Wc  = wb + 65536,  *Wo  = wb + 98304;
  ushort* bl0 = wb + 102400, *bl1 = wb + 102528, *bc = wb + 102656, *bo = wb + 102784;

  WPtrs w;
  w.p[0] = d_in[2];  w.p[1] = d_in[4];  w.p[2] = d_in[5];  w.p[3] = d_in[7];
  w.p[4] = d_in[8];  w.p[5] = d_in[10]; w.p[6] = d_in[3];  w.p[7] = d_in[6];
  w.p[8] = d_in[9];  w.p[9] = d_in[11];

  const int gblocks = (NN + 127) / 128;        // 782
  const int n4 = NN * D / 4;
  const int agrid = (NN + 3) / 4;              // 25,000 (4 nodes/block)

  sniff_k<<<1, 64, 0, stream>>>((const ushort*)x_in, (const unsigned int*)ei, flags);
  convert_idx_k<<<(2 * NE + 255) / 256, 256, 0, stream>>>(ei, flags, idx, 2 * NE);
  convert_x_k<<<(n4 + 255) / 256, 256, 0, stream>>>(x_in, flags, buf2);
  convert_w_k<<<(WTOT + 255) / 256, 256, 0, stream>>>(w, flags, wb);

  // ---- build CSR via two-level multisplit (LDS atomics, coalesced writes) --
  (void)hipMemsetAsync(bhist, 0, NBKT * sizeof(int), stream);
  hist_k<<<256, 256, 0, stream>>>(dst, bhist);
  scanb_k<<<1, 256, 0, stream>>>(bhist, bstart, bcur);
  msplit_k<<<MS_NBLK, 512, 0, stream>>>(src, dst, bcur, ebuf);
  csr_k<<<NBKT, 512, 0, stream>>>(ebuf, bstart, off, nbr);

  // ---- layer 0: x=buf2 -> mean=dscr -> h=buf1 -> x1=dscr -------------------
  agg_k<<<agrid, 256, 0, stream>>>(buf2, nbr, off, dscr);
  gemm_dual<<<gblocks, 256, 0, stream>>>(dscr, buf2, Wl0, Wr0, D, bl0, buf1, NN);      // h
  gemm_dual<<<gblocks, 256, 0, stream>>>(buf2, buf1, Wc, Wc + D, 2 * D, bc, dscr, NN); // x1

  // ---- layer 1: x1=dscr -> mean=buf2 -> h=buf1 -> x2=buf2 ------------------
  agg_k<<<agrid, 256, 0, stream>>>(dscr, nbr, off, buf2);
  gemm_dual<<<gblocks, 256, 0, stream>>>(buf2, dscr, Wl1, Wr1, D, bl1, buf1, NN);      // h
  gemm_dual<<<gblocks, 256, 0, stream>>>(dscr, buf1, Wc, Wc + D, 2 * D, bc, buf2, NN); // x2

  // ---- edge classifier: factored P-GEMM + gather-sum -----------------------
  gemm_po<<<(NN + 63) / 64, 256, 0, stream>>>(buf2, Wo, P);
  edge_sum_k<<<(4 * NE + 255) / 256, 256, 0, stream>>>(P, src, dst, bo, flags, d_out, NE);
}